// Round 14
// baseline (587.598 us; speedup 1.0000x reference)
//
#include <hip/hip_runtime.h>

#define B_ 64
#define L_ 2048
#define G_ 512
#define F_ 3072
#define N_ 5632
#define NT_ 360448
#define EG_ 16384
#define E_ 1048576
#define EPS_ 1e-5f
#define CST_ 66      // cat tile stride in ushorts (33 dwords, odd -> ~2-way banks)
#define KTOT_ 3584   // md GEMM K = G + F
#define KCH_ 224     // md GEMM K-chunk (16 chunks)
#define TCAP_ 384    // per-tile edge capacity (realized max span ~255)

typedef __attribute__((ext_vector_type(8))) short bf8v;
typedef __attribute__((ext_vector_type(4))) float f4v;

__device__ __forceinline__ unsigned short f2bf(float f){
  unsigned int u=__float_as_uint(f);
  unsigned int r=(u + 0x7fffu + ((u>>16)&1u))>>16;
  return (unsigned short)r;
}
__device__ __forceinline__ float bf2f(unsigned short h){
  return __uint_as_float(((unsigned int)h)<<16);
}

// ---------------- single prep dispatch ----------------
// blocks 0..87      : per-tile CSR build (LDS hist -> scan -> scatter), packed (src|dst<<16)
// blocks 88..599    : wcat build + outmd demand init
// blocks 600..11863 : encoder + fused LN (produces hnA)
__global__ __launch_bounds__(256) void k_prep(const int* __restrict__ ei,
    unsigned short* __restrict__ wcat,
    const float* __restrict__ wrel, const float* __restrict__ wroot,
    int* __restrict__ offT, int* __restrict__ srcs2,
    const float* __restrict__ x, const int* __restrict__ loci, float* __restrict__ outmd,
    unsigned short* __restrict__ hn, const float* __restrict__ ew, const float* __restrict__ eb,
    const float* __restrict__ lng, const float* __restrict__ lnb){
  int bid=blockIdx.x, tid=threadIdx.x;
  if(bid>=600){
    // ---- encoder + LN ----
    int lane=tid&63, wid=tid>>6;
    int node0=(bid-600)*32+wid*8;
    float w[7];
    #pragma unroll
    for(int k=0;k<7;k++) w[k]=ew[lane*7+k];
    float bias=eb[lane], gam=lng[lane], bet=lnb[lane];
    for(int t=0;t<8;t++){
      long n=node0+t;
      float acc=bias;
      #pragma unroll
      for(int k=0;k<7;k++) acc += x[n*7+k]*w[k];
      acc=fmaxf(acc,0.f);
      float s1=acc, s2=acc*acc;
      #pragma unroll
      for(int o=32;o>0;o>>=1){ s1+=__shfl_xor(s1,o,64); s2+=__shfl_xor(s2,o,64); }
      float mu=s1*(1.f/64.f);
      float var=s2*(1.f/64.f)-mu*mu;
      float inv=rsqrtf(var+EPS_);
      hn[n*64+lane]=f2bf((acc-mu)*inv*gam+bet);
    }
    return;
  }
  if(bid>=88){
    int i=(bid-88)*256+tid;          // 512 blocks -> 131072 = B_*L_
    if(i<B_*L_) outmd[i]=x[(long)loci[i]*7];
    if(i<32768){
      int l=i>>13; int rest=i&8191; int n=rest>>7; int k=rest&127;
      float v=(k<64)? wrel[((long)l*64+n)*64+k] : wroot[((long)l*64+n)*64+(k-64)];
      wcat[i]=f2bf(v);
    }
    return;
  }
  __shared__ int cnt64[64], cur64[64];
  int nb=bid*64;
  if(tid<64) cnt64[tid]=0;
  __syncthreads();
  for(int e=tid;e<EG_;e+=256){
    int d=ei[E_+e];
    unsigned t=(unsigned)(d-nb);
    if(t<64u) atomicAdd(&cnt64[t],1);
  }
  __syncthreads();
  if(tid<64){
    int v=cnt64[tid], s=v;
    #pragma unroll
    for(int o=1;o<64;o<<=1){ int u=__shfl_up(s,o,64); if(tid>=o) s+=u; }
    int ex=s-v;
    offT[bid*65+tid]=ex;
    cur64[tid]=ex;
    if(tid==63) offT[bid*65+64]=s;
  }
  __syncthreads();
  for(int e=tid;e<EG_;e+=256){
    int s=ei[e];
    int d=ei[E_+e];
    unsigned t=(unsigned)(d-nb);
    if(t<64u){
      int p=atomicAdd(&cur64[t],1);
      if(p<TCAP_) srcs2[bid*TCAP_+p]=s|(d<<16);
    }
  }
}

// ---------------- fused layer: deep-pipelined gather -> MFMA -> epilogue (barrier-free) ----------------
// wave w owns dst rows [w*16,w*16+16); lane = channel. 8-wide groups; words fetched 3 ahead,
// rows issued 2 ahead; tail padded with (dst=w16+15, value 0) synthetic edges.
__global__ __launch_bounds__(256,8) void k_layer(const unsigned short* __restrict__ hs,
    unsigned short* __restrict__ hd, const int* __restrict__ offT, const int* __restrict__ srcs2,
    const unsigned short* __restrict__ wcat, const float* __restrict__ brel,
    const float* __restrict__ lng, const float* __restrict__ lnb, int do_ln){
  __shared__ unsigned short cat[64*CST_];
  int tid=threadIdx.x;
  int w=tid>>6, lane=tid&63;
  int bid=blockIdx.x;
  const int P=N_/64;                 // 88 tiles per graph
  int r8=bid/(8*P), rem=bid%(8*P);
  int xcd=rem&7, jj=rem>>3, g=r8*8+xcd;   // one graph per XCD's L2
  int nodebase=jj*64;
  const unsigned short* hg = hs + (size_t)g*N_*64;
  int w16=w*16;

  // ---- phase 1: 8-wide deep-pipelined gather with sorted-dst running flush ----
  {
    int kb=__builtin_amdgcn_readfirstlane(offT[jj*65+w16]);
    int ke=__builtin_amdgcn_readfirstlane(offT[jj*65+w16+16]);
    const int* esp=srcs2 + jj*TCAP_;
    const int padw=(w16+15)<<16;       // synthetic edge: dst=last-owned row, value forced 0
    float acc=0.f;
    int dcur=w16;
#define FLUSH_(dd) while(dcur<(dd)){ cat[dcur*CST_+lane]=f2bf(acc); acc=0.f; dcur++; }
#define GETW_(arr,gg) { int kk_=kb+(gg)*8; \
  _Pragma("unroll") for(int t=0;t<8;t++){ int k_=kk_+t; int km_=(k_<ke)?k_:(ke-1); \
    int wd_=esp[km_]; arr[t]=(k_<ke)?wd_:padw; } }
#define ROWS_(dst,warr) { _Pragma("unroll") for(int t=0;t<8;t++){ \
    dst[t]=hg[(size_t)((warr[t])&0xffff)*64+lane]; } }
    int n8=(ke-kb+7)>>3;
    int uw[8],vw[8],ww[8];
    unsigned short a8[8],b8[8];
    GETW_(uw,0); GETW_(vw,1); GETW_(ww,2);
    ROWS_(a8,uw); ROWS_(b8,vw);
    for(int gi=0; gi<n8; gi++){
      int xw[8];
      GETW_(xw,gi+3);                  // words 3 groups ahead
      unsigned short c8[8];
      ROWS_(c8,ww);                    // rows 2 groups ahead (words fetched last iter)
      int kk=kb+gi*8;
      #pragma unroll
      for(int t=0;t<8;t++){            // consume current group
        int d=(uw[t]>>16)-nodebase;
        FLUSH_(d);
        float val=bf2f(a8[t]);
        acc += (kk+t<ke)? val : 0.f;
      }
      #pragma unroll
      for(int t=0;t<8;t++){ uw[t]=vw[t]; vw[t]=ww[t]; ww[t]=xw[t]; a8[t]=b8[t]; b8[t]=c8[t]; }
    }
    FLUSH_(w16+16);
#undef FLUSH_
#undef GETW_
#undef ROWS_
  }
  // no barrier: wave w writes and reads only cat rows [w16, w16+16)

  // ---- phase 2: MFMA [agg|root] @ Wcat^T, fused epilogue ----
  int m=lane&15, quad=lane>>4;
  int row=w16+m;
  const unsigned short* arow=&cat[row*CST_];
  bf8v af0=*(const bf8v*)(arow + quad*8);
  bf8v af1=*(const bf8v*)(arow + 32 + quad*8);
  const unsigned short* hrow=hg+(size_t)(nodebase+row)*64;
  bf8v af2=*(const bf8v*)(hrow+quad*8);
  bf8v af3=*(const bf8v*)(hrow+32+quad*8);
  f4v acc[4];
  float bias_nt[4], g_nt[4], b_nt[4];
  #pragma unroll
  for(int nt=0;nt<4;nt++){
    int c=nt*16+m;
    bias_nt[nt]=brel[c];
    g_nt[nt]=lng[c]; b_nt[nt]=lnb[c];
    acc[nt]=(f4v){0.f,0.f,0.f,0.f};
    const unsigned short* wrow=wcat + (long)c*128 + quad*8;
    bf8v b0=*(const bf8v*)(wrow);
    bf8v b1=*(const bf8v*)(wrow+32);
    bf8v b2=*(const bf8v*)(wrow+64);
    bf8v b3=*(const bf8v*)(wrow+96);
    acc[nt]=__builtin_amdgcn_mfma_f32_16x16x32_bf16(af0,b0,acc[nt],0,0,0);
    acc[nt]=__builtin_amdgcn_mfma_f32_16x16x32_bf16(af1,b1,acc[nt],0,0,0);
    acc[nt]=__builtin_amdgcn_mfma_f32_16x16x32_bf16(af2,b2,acc[nt],0,0,0);
    acc[nt]=__builtin_amdgcn_mfma_f32_16x16x32_bf16(af3,b3,acc[nt],0,0,0);
  }
  float v[4][4];
  #pragma unroll
  for(int nt=0;nt<4;nt++)
    #pragma unroll
    for(int r=0;r<4;r++)
      v[nt][r]=fmaxf(acc[nt][r]+bias_nt[nt],0.f);
  if(do_ln){
    #pragma unroll
    for(int r=0;r<4;r++){
      float rs=v[0][r]+v[1][r]+v[2][r]+v[3][r];
      float rss=v[0][r]*v[0][r]+v[1][r]*v[1][r]+v[2][r]*v[2][r]+v[3][r]*v[3][r];
      #pragma unroll
      for(int o=1;o<16;o<<=1){ rs+=__shfl_xor(rs,o,64); rss+=__shfl_xor(rss,o,64); }
      float mu=rs*(1.f/64.f);
      float var=rss*(1.f/64.f)-mu*mu;
      float inv=rsqrtf(var+EPS_);
      #pragma unroll
      for(int nt=0;nt<4;nt++) v[nt][r]=(v[nt][r]-mu)*inv*g_nt[nt]+b_nt[nt];
    }
  }
  size_t rowbase=(size_t)g*N_ + nodebase + w16 + quad*4;
  #pragma unroll
  for(int r=0;r<4;r++){
    unsigned short* out=hd + (rowbase+r)*64;
    #pragma unroll
    for(int nt=0;nt<4;nt++) out[nt*16+m]=f2bf(v[nt][r]);
  }
}

// ---------------- merged readouts; also emit double-bf16 pf rows for md GEMM ----------------
__global__ __launch_bounds__(256) void k_readout2(const unsigned short* __restrict__ h,
    const int* __restrict__ prodi, const int* __restrict__ linei,
    const float* __restrict__ pw, const float* __restrict__ pb,
    const float* __restrict__ fw, const float* __restrict__ fb,
    float* __restrict__ outp, float* __restrict__ outf,
    unsigned short* __restrict__ pfhi, unsigned short* __restrict__ pflo){
  int i=blockIdx.x*256+threadIdx.x;
  const int MP=B_*G_;
  const int MT=MP+B_*F_;
  if(i>=MT) return;
  bool isp=i<MP;
  int j=isp? i : i-MP;
  long n=isp? (long)prodi[j] : (long)linei[j];
  const float* wv=isp? pw:fw;
  float acc=isp? pb[0]:fb[0];
  const uint4* hp=(const uint4*)(h+n*64);
  #pragma unroll
  for(int c=0;c<8;c++){
    uint4 u=hp[c];
    unsigned int uu[4]={u.x,u.y,u.z,u.w};
    #pragma unroll
    for(int q=0;q<4;q++){
      float lo=__uint_as_float(uu[q]<<16);
      float hi=__uint_as_float(uu[q]&0xffff0000u);
      acc += lo*wv[c*8+2*q] + hi*wv[c*8+2*q+1];
    }
  }
  int b,kcol;
  if(isp){ outp[j]=acc; b=j/G_; kcol=j%G_; }
  else   { outf[j]=acc; b=j/F_; kcol=G_+j%F_; }
  unsigned short hi=f2bf(acc);
  pfhi[(long)b*KTOT_+kcol]=hi;
  pflo[(long)b*KTOT_+kcol]=f2bf(acc-bf2f(hi));
}

// ---------------- md dense GEMM: outmd[b][l] -= sum_k mask[l][k]*pf[b][k] ----------------
// 512 blocks = 32 loc-tiles x 16 K-chunks; outmd pre-initialized with demand by k_prep.
__global__ __launch_bounds__(256) void k_md_gemm(const float* __restrict__ gm, const float* __restrict__ lm,
    const unsigned short* __restrict__ pfhi, const unsigned short* __restrict__ pflo,
    float* __restrict__ outmd){
  int tid=threadIdx.x;
  int w=tid>>6, lane=tid&63;
  int m=lane&15, quad=lane>>4;
  int lb=blockIdx.x>>4, kc=blockIdx.x&15;
  int l=lb*64 + w*16 + m;              // A (mask) row for this lane
  f4v acc[4];
  #pragma unroll
  for(int nt=0;nt<4;nt++) acc[nt]=(f4v){0.f,0.f,0.f,0.f};
  int kk0=kc*KCH_;
  for(int s=0;s<KCH_/32;s++){
    int kk=kk0+s*32;                   // 32-steps never straddle G_ (512%32==0)
    const float* ap = (kk<G_)? gm + (long)l*G_ + kk : lm + (long)l*F_ + (kk-G_);
    float4 a0=*(const float4*)(ap+quad*8);
    float4 a1=*(const float4*)(ap+quad*8+4);
    bf8v af;
    af[0]=(short)f2bf(a0.x); af[1]=(short)f2bf(a0.y);
    af[2]=(short)f2bf(a0.z); af[3]=(short)f2bf(a0.w);
    af[4]=(short)f2bf(a1.x); af[5]=(short)f2bf(a1.y);
    af[6]=(short)f2bf(a1.z); af[7]=(short)f2bf(a1.w);
    #pragma unroll
    for(int nt=0;nt<4;nt++){
      int b=nt*16+m;
      const unsigned short* bp=pfhi + (long)b*KTOT_ + kk + quad*8;
      const unsigned short* lp=pflo + (long)b*KTOT_ + kk + quad*8;
      bf8v bh=*(const bf8v*)bp;
      bf8v bl=*(const bf8v*)lp;
      acc[nt]=__builtin_amdgcn_mfma_f32_16x16x32_bf16(af,bh,acc[nt],0,0,0);
      acc[nt]=__builtin_amdgcn_mfma_f32_16x16x32_bf16(af,bl,acc[nt],0,0,0);
    }
  }
  int lrow=lb*64 + w*16 + quad*4;
  #pragma unroll
  for(int r=0;r<4;r++)
    #pragma unroll
    for(int nt=0;nt<4;nt++)
      atomicAdd(&outmd[(long)(nt*16+m)*L_ + lrow+r], -acc[nt][r]);
}

extern "C" void kernel_launch(void* const* d_in, const int* in_sizes, int n_in,
                              void* d_out, int out_size, void* d_ws, size_t ws_size,
                              hipStream_t stream){
  const float* x    =(const float*)d_in[0];
  const int*   ei   =(const int*)d_in[1];
  const int*   prodi=(const int*)d_in[2];
  const int*   linei=(const int*)d_in[3];
  const int*   loci =(const int*)d_in[4];
  const float* ew   =(const float*)d_in[5];
  const float* eb   =(const float*)d_in[6];
  const float* lng  =(const float*)d_in[7];
  const float* lnb  =(const float*)d_in[8];
  const float* wrel =(const float*)d_in[9];
  const float* brel =(const float*)d_in[10];
  const float* wroot=(const float*)d_in[11];
  const float* pw   =(const float*)d_in[12];
  const float* pb   =(const float*)d_in[13];
  const float* fw   =(const float*)d_in[14];
  const float* fb   =(const float*)d_in[15];
  const float* gm   =(const float*)d_in[16];
  const float* lm   =(const float*)d_in[17];

  char* ws=(char*)d_ws;
  unsigned short* hnA =(unsigned short*)ws;                        // NT*64 bf16
  unsigned short* hnB =hnA + (size_t)NT_*64;                       // NT*64 bf16
  unsigned short* wcat=hnB + (size_t)NT_*64;                       // 32768 bf16
  unsigned short* pfhi=wcat + 32768;                               // B*KTOT bf16
  unsigned short* pflo=pfhi + (size_t)B_*KTOT_;                    // B*KTOT bf16
  int* offT =(int*)(pflo + (size_t)B_*KTOT_);                      // 88*65 int
  int* srcs2=offT + 88*65;                                         // 88*TCAP int

  float* outp =(float*)d_out;
  float* outf =outp + (size_t)B_*G_;
  float* outmd=outf + (size_t)B_*F_;

  k_prep<<<600+NT_/32,256,0,stream>>>(ei,wcat,wrel,wroot,offT,srcs2,
                                      x,loci,outmd,hnA,ew,eb,lng,lnb);
  for(int i=0;i<4;i++){
    const unsigned short* hs=(i&1)?hnB:hnA;
    unsigned short* hd=(i&1)?hnA:hnB;
    k_layer<<<B_*(N_/64),256,0,stream>>>(hs,hd,offT,srcs2,wcat+(size_t)i*8192,
        brel+(size_t)i*64,lng,lnb,(i<3)?1:0);
  }
  // after 4 layers (A->B->A->B->A) result is in hnA
  {
    int MT=B_*(G_+F_);
    k_readout2<<<(MT+255)/256,256,0,stream>>>(hnA,prodi,linei,pw,pb,fw,fb,outp,outf,pfhi,pflo);
  }
  k_md_gemm<<<512,256,0,stream>>>(gm,lm,pfhi,pflo,outmd);
}

// Round 15
// 489.718 us; speedup vs baseline: 1.1999x; 1.1999x over previous
//
#include <hip/hip_runtime.h>

#define B_ 64
#define L_ 2048
#define G_ 512
#define F_ 3072
#define N_ 5632
#define NT_ 360448
#define EG_ 16384
#define E_ 1048576
#define EPS_ 1e-5f
#define CST_ 66      // cat tile stride in ushorts (33 dwords, odd -> ~2-way banks)
#define KTOT_ 3584   // md GEMM K = G + F
#define KCH_ 224     // md GEMM K-chunk (16 chunks)
#define TCAP_ 384    // per-tile edge capacity (realized max span ~255)

typedef __attribute__((ext_vector_type(8))) short bf8v;
typedef __attribute__((ext_vector_type(4))) float f4v;

__device__ __forceinline__ unsigned short f2bf(float f){
  unsigned int u=__float_as_uint(f);
  unsigned int r=(u + 0x7fffu + ((u>>16)&1u))>>16;
  return (unsigned short)r;
}
__device__ __forceinline__ float bf2f(unsigned short h){
  return __uint_as_float(((unsigned int)h)<<16);
}

// ---------------- single prep dispatch ----------------
// blocks 0..87      : per-tile CSR build (LDS hist -> scan -> scatter), packed (src|dst<<16)
// blocks 88..599    : wcat build + outmd demand init
// blocks 600..11863 : encoder + fused LN (produces hnA)
__global__ __launch_bounds__(256) void k_prep(const int* __restrict__ ei,
    unsigned short* __restrict__ wcat,
    const float* __restrict__ wrel, const float* __restrict__ wroot,
    int* __restrict__ offT, int* __restrict__ srcs2,
    const float* __restrict__ x, const int* __restrict__ loci, float* __restrict__ outmd,
    unsigned short* __restrict__ hn, const float* __restrict__ ew, const float* __restrict__ eb,
    const float* __restrict__ lng, const float* __restrict__ lnb){
  int bid=blockIdx.x, tid=threadIdx.x;
  if(bid>=600){
    // ---- encoder + LN ----
    int lane=tid&63, wid=tid>>6;
    int node0=(bid-600)*32+wid*8;
    float w[7];
    #pragma unroll
    for(int k=0;k<7;k++) w[k]=ew[lane*7+k];
    float bias=eb[lane], gam=lng[lane], bet=lnb[lane];
    for(int t=0;t<8;t++){
      long n=node0+t;
      float acc=bias;
      #pragma unroll
      for(int k=0;k<7;k++) acc += x[n*7+k]*w[k];
      acc=fmaxf(acc,0.f);
      float s1=acc, s2=acc*acc;
      #pragma unroll
      for(int o=32;o>0;o>>=1){ s1+=__shfl_xor(s1,o,64); s2+=__shfl_xor(s2,o,64); }
      float mu=s1*(1.f/64.f);
      float var=s2*(1.f/64.f)-mu*mu;
      float inv=rsqrtf(var+EPS_);
      hn[n*64+lane]=f2bf((acc-mu)*inv*gam+bet);
    }
    return;
  }
  if(bid>=88){
    int i=(bid-88)*256+tid;          // 512 blocks -> 131072 = B_*L_
    if(i<B_*L_) outmd[i]=x[(long)loci[i]*7];
    if(i<32768){
      int l=i>>13; int rest=i&8191; int n=rest>>7; int k=rest&127;
      float v=(k<64)? wrel[((long)l*64+n)*64+k] : wroot[((long)l*64+n)*64+(k-64)];
      wcat[i]=f2bf(v);
    }
    return;
  }
  __shared__ int cnt64[64], cur64[64];
  int nb=bid*64;
  if(tid<64) cnt64[tid]=0;
  __syncthreads();
  for(int e=tid;e<EG_;e+=256){
    int d=ei[E_+e];
    unsigned t=(unsigned)(d-nb);
    if(t<64u) atomicAdd(&cnt64[t],1);
  }
  __syncthreads();
  if(tid<64){
    int v=cnt64[tid], s=v;
    #pragma unroll
    for(int o=1;o<64;o<<=1){ int u=__shfl_up(s,o,64); if(tid>=o) s+=u; }
    int ex=s-v;
    offT[bid*65+tid]=ex;
    cur64[tid]=ex;
    if(tid==63) offT[bid*65+64]=s;
  }
  __syncthreads();
  for(int e=tid;e<EG_;e+=256){
    int s=ei[e];
    int d=ei[E_+e];
    unsigned t=(unsigned)(d-nb);
    if(t<64u){
      int p=atomicAdd(&cur64[t],1);
      if(p<TCAP_) srcs2[bid*TCAP_+p]=s|(d<<16);
    }
  }
}

// ---------------- fused layer: deep-pipelined gather -> MFMA -> epilogue (barrier-free) ----------------
// wave w owns dst rows [w*16,w*16+16); lane = channel. 8-wide groups; words fetched 3 ahead,
// rows issued 2 ahead; tail padded with (dst=w16+15, value 0) synthetic edges.
// launch_bounds(256,4): 128-VGPR cap so the pipeline state fits WITHOUT scratch spills
// (R14's (256,8) forced a 64-VGPR cap -> 85 MB of spill traffic, 105 us).
__global__ __launch_bounds__(256,4) void k_layer(const unsigned short* __restrict__ hs,
    unsigned short* __restrict__ hd, const int* __restrict__ offT, const int* __restrict__ srcs2,
    const unsigned short* __restrict__ wcat, const float* __restrict__ brel,
    const float* __restrict__ lng, const float* __restrict__ lnb, int do_ln){
  __shared__ unsigned short cat[64*CST_];
  int tid=threadIdx.x;
  int w=tid>>6, lane=tid&63;
  int bid=blockIdx.x;
  const int P=N_/64;                 // 88 tiles per graph
  int r8=bid/(8*P), rem=bid%(8*P);
  int xcd=rem&7, jj=rem>>3, g=r8*8+xcd;   // one graph per XCD's L2
  int nodebase=jj*64;
  const unsigned short* hg = hs + (size_t)g*N_*64;
  int w16=w*16;

  // ---- phase 1: 8-wide deep-pipelined gather with sorted-dst running flush ----
  {
    int kb=__builtin_amdgcn_readfirstlane(offT[jj*65+w16]);
    int ke=__builtin_amdgcn_readfirstlane(offT[jj*65+w16+16]);
    const int* esp=srcs2 + jj*TCAP_;
    const int padw=(w16+15)<<16;       // synthetic edge: dst=last-owned row, value forced 0
    float acc=0.f;
    int dcur=w16;
#define FLUSH_(dd) while(dcur<(dd)){ cat[dcur*CST_+lane]=f2bf(acc); acc=0.f; dcur++; }
#define GETW_(arr,gg) { int kk_=kb+(gg)*8; \
  _Pragma("unroll") for(int t=0;t<8;t++){ int k_=kk_+t; int km_=(k_<ke)?k_:(ke-1); \
    int wd_=esp[km_]; arr[t]=(k_<ke)?wd_:padw; } }
#define ROWS_(dst,warr) { _Pragma("unroll") for(int t=0;t<8;t++){ \
    dst[t]=hg[(size_t)((warr[t])&0xffff)*64+lane]; } }
    int n8=(ke-kb+7)>>3;
    int uw[8],vw[8],ww[8];
    unsigned short a8[8],b8[8];
    GETW_(uw,0); GETW_(vw,1); GETW_(ww,2);
    ROWS_(a8,uw); ROWS_(b8,vw);
    for(int gi=0; gi<n8; gi++){
      int xw[8];
      GETW_(xw,gi+3);                  // words 3 groups ahead
      unsigned short c8[8];
      ROWS_(c8,ww);                    // rows 2 groups ahead (words fetched last iter)
      int kk=kb+gi*8;
      #pragma unroll
      for(int t=0;t<8;t++){            // consume current group
        int d=(uw[t]>>16)-nodebase;
        FLUSH_(d);
        float val=bf2f(a8[t]);
        acc += (kk+t<ke)? val : 0.f;
      }
      #pragma unroll
      for(int t=0;t<8;t++){ uw[t]=vw[t]; vw[t]=ww[t]; ww[t]=xw[t]; a8[t]=b8[t]; b8[t]=c8[t]; }
    }
    FLUSH_(w16+16);
#undef FLUSH_
#undef GETW_
#undef ROWS_
  }
  // no barrier: wave w writes and reads only cat rows [w16, w16+16)

  // ---- phase 2: MFMA [agg|root] @ Wcat^T, fused epilogue ----
  int m=lane&15, quad=lane>>4;
  int row=w16+m;
  const unsigned short* arow=&cat[row*CST_];
  bf8v af0=*(const bf8v*)(arow + quad*8);
  bf8v af1=*(const bf8v*)(arow + 32 + quad*8);
  const unsigned short* hrow=hg+(size_t)(nodebase+row)*64;
  bf8v af2=*(const bf8v*)(hrow+quad*8);
  bf8v af3=*(const bf8v*)(hrow+32+quad*8);
  f4v acc[4];
  float bias_nt[4], g_nt[4], b_nt[4];
  #pragma unroll
  for(int nt=0;nt<4;nt++){
    int c=nt*16+m;
    bias_nt[nt]=brel[c];
    g_nt[nt]=lng[c]; b_nt[nt]=lnb[c];
    acc[nt]=(f4v){0.f,0.f,0.f,0.f};
    const unsigned short* wrow=wcat + (long)c*128 + quad*8;
    bf8v b0=*(const bf8v*)(wrow);
    bf8v b1=*(const bf8v*)(wrow+32);
    bf8v b2=*(const bf8v*)(wrow+64);
    bf8v b3=*(const bf8v*)(wrow+96);
    acc[nt]=__builtin_amdgcn_mfma_f32_16x16x32_bf16(af0,b0,acc[nt],0,0,0);
    acc[nt]=__builtin_amdgcn_mfma_f32_16x16x32_bf16(af1,b1,acc[nt],0,0,0);
    acc[nt]=__builtin_amdgcn_mfma_f32_16x16x32_bf16(af2,b2,acc[nt],0,0,0);
    acc[nt]=__builtin_amdgcn_mfma_f32_16x16x32_bf16(af3,b3,acc[nt],0,0,0);
  }
  float v[4][4];
  #pragma unroll
  for(int nt=0;nt<4;nt++)
    #pragma unroll
    for(int r=0;r<4;r++)
      v[nt][r]=fmaxf(acc[nt][r]+bias_nt[nt],0.f);
  if(do_ln){
    #pragma unroll
    for(int r=0;r<4;r++){
      float rs=v[0][r]+v[1][r]+v[2][r]+v[3][r];
      float rss=v[0][r]*v[0][r]+v[1][r]*v[1][r]+v[2][r]*v[2][r]+v[3][r]*v[3][r];
      #pragma unroll
      for(int o=1;o<16;o<<=1){ rs+=__shfl_xor(rs,o,64); rss+=__shfl_xor(rss,o,64); }
      float mu=rs*(1.f/64.f);
      float var=rss*(1.f/64.f)-mu*mu;
      float inv=rsqrtf(var+EPS_);
      #pragma unroll
      for(int nt=0;nt<4;nt++) v[nt][r]=(v[nt][r]-mu)*inv*g_nt[nt]+b_nt[nt];
    }
  }
  size_t rowbase=(size_t)g*N_ + nodebase + w16 + quad*4;
  #pragma unroll
  for(int r=0;r<4;r++){
    unsigned short* out=hd + (rowbase+r)*64;
    #pragma unroll
    for(int nt=0;nt<4;nt++) out[nt*16+m]=f2bf(v[nt][r]);
  }
}

// ---------------- merged readouts; also emit double-bf16 pf rows for md GEMM ----------------
__global__ __launch_bounds__(256) void k_readout2(const unsigned short* __restrict__ h,
    const int* __restrict__ prodi, const int* __restrict__ linei,
    const float* __restrict__ pw, const float* __restrict__ pb,
    const float* __restrict__ fw, const float* __restrict__ fb,
    float* __restrict__ outp, float* __restrict__ outf,
    unsigned short* __restrict__ pfhi, unsigned short* __restrict__ pflo){
  int i=blockIdx.x*256+threadIdx.x;
  const int MP=B_*G_;
  const int MT=MP+B_*F_;
  if(i>=MT) return;
  bool isp=i<MP;
  int j=isp? i : i-MP;
  long n=isp? (long)prodi[j] : (long)linei[j];
  const float* wv=isp? pw:fw;
  float acc=isp? pb[0]:fb[0];
  const uint4* hp=(const uint4*)(h+n*64);
  #pragma unroll
  for(int c=0;c<8;c++){
    uint4 u=hp[c];
    unsigned int uu[4]={u.x,u.y,u.z,u.w};
    #pragma unroll
    for(int q=0;q<4;q++){
      float lo=__uint_as_float(uu[q]<<16);
      float hi=__uint_as_float(uu[q]&0xffff0000u);
      acc += lo*wv[c*8+2*q] + hi*wv[c*8+2*q+1];
    }
  }
  int b,kcol;
  if(isp){ outp[j]=acc; b=j/G_; kcol=j%G_; }
  else   { outf[j]=acc; b=j/F_; kcol=G_+j%F_; }
  unsigned short hi=f2bf(acc);
  pfhi[(long)b*KTOT_+kcol]=hi;
  pflo[(long)b*KTOT_+kcol]=f2bf(acc-bf2f(hi));
}

// ---------------- md dense GEMM: outmd[b][l] -= sum_k mask[l][k]*pf[b][k] ----------------
// 512 blocks = 32 loc-tiles x 16 K-chunks; outmd pre-initialized with demand by k_prep.
__global__ __launch_bounds__(256) void k_md_gemm(const float* __restrict__ gm, const float* __restrict__ lm,
    const unsigned short* __restrict__ pfhi, const unsigned short* __restrict__ pflo,
    float* __restrict__ outmd){
  int tid=threadIdx.x;
  int w=tid>>6, lane=tid&63;
  int m=lane&15, quad=lane>>4;
  int lb=blockIdx.x>>4, kc=blockIdx.x&15;
  int l=lb*64 + w*16 + m;              // A (mask) row for this lane
  f4v acc[4];
  #pragma unroll
  for(int nt=0;nt<4;nt++) acc[nt]=(f4v){0.f,0.f,0.f,0.f};
  int kk0=kc*KCH_;
  for(int s=0;s<KCH_/32;s++){
    int kk=kk0+s*32;                   // 32-steps never straddle G_ (512%32==0)
    const float* ap = (kk<G_)? gm + (long)l*G_ + kk : lm + (long)l*F_ + (kk-G_);
    float4 a0=*(const float4*)(ap+quad*8);
    float4 a1=*(const float4*)(ap+quad*8+4);
    bf8v af;
    af[0]=(short)f2bf(a0.x); af[1]=(short)f2bf(a0.y);
    af[2]=(short)f2bf(a0.z); af[3]=(short)f2bf(a0.w);
    af[4]=(short)f2bf(a1.x); af[5]=(short)f2bf(a1.y);
    af[6]=(short)f2bf(a1.z); af[7]=(short)f2bf(a1.w);
    #pragma unroll
    for(int nt=0;nt<4;nt++){
      int b=nt*16+m;
      const unsigned short* bp=pfhi + (long)b*KTOT_ + kk + quad*8;
      const unsigned short* lp=pflo + (long)b*KTOT_ + kk + quad*8;
      bf8v bh=*(const bf8v*)bp;
      bf8v bl=*(const bf8v*)lp;
      acc[nt]=__builtin_amdgcn_mfma_f32_16x16x32_bf16(af,bh,acc[nt],0,0,0);
      acc[nt]=__builtin_amdgcn_mfma_f32_16x16x32_bf16(af,bl,acc[nt],0,0,0);
    }
  }
  int lrow=lb*64 + w*16 + quad*4;
  #pragma unroll
  for(int r=0;r<4;r++)
    #pragma unroll
    for(int nt=0;nt<4;nt++)
      atomicAdd(&outmd[(long)(nt*16+m)*L_ + lrow+r], -acc[nt][r]);
}

extern "C" void kernel_launch(void* const* d_in, const int* in_sizes, int n_in,
                              void* d_out, int out_size, void* d_ws, size_t ws_size,
                              hipStream_t stream){
  const float* x    =(const float*)d_in[0];
  const int*   ei   =(const int*)d_in[1];
  const int*   prodi=(const int*)d_in[2];
  const int*   linei=(const int*)d_in[3];
  const int*   loci =(const int*)d_in[4];
  const float* ew   =(const float*)d_in[5];
  const float* eb   =(const float*)d_in[6];
  const float* lng  =(const float*)d_in[7];
  const float* lnb  =(const float*)d_in[8];
  const float* wrel =(const float*)d_in[9];
  const float* brel =(const float*)d_in[10];
  const float* wroot=(const float*)d_in[11];
  const float* pw   =(const float*)d_in[12];
  const float* pb   =(const float*)d_in[13];
  const float* fw   =(const float*)d_in[14];
  const float* fb   =(const float*)d_in[15];
  const float* gm   =(const float*)d_in[16];
  const float* lm   =(const float*)d_in[17];

  char* ws=(char*)d_ws;
  unsigned short* hnA =(unsigned short*)ws;                        // NT*64 bf16
  unsigned short* hnB =hnA + (size_t)NT_*64;                       // NT*64 bf16
  unsigned short* wcat=hnB + (size_t)NT_*64;                       // 32768 bf16
  unsigned short* pfhi=wcat + 32768;                               // B*KTOT bf16
  unsigned short* pflo=pfhi + (size_t)B_*KTOT_;                    // B*KTOT bf16
  int* offT =(int*)(pflo + (size_t)B_*KTOT_);                      // 88*65 int
  int* srcs2=offT + 88*65;                                         // 88*TCAP int

  float* outp =(float*)d_out;
  float* outf =outp + (size_t)B_*G_;
  float* outmd=outf + (size_t)B_*F_;

  k_prep<<<600+NT_/32,256,0,stream>>>(ei,wcat,wrel,wroot,offT,srcs2,
                                      x,loci,outmd,hnA,ew,eb,lng,lnb);
  for(int i=0;i<4;i++){
    const unsigned short* hs=(i&1)?hnB:hnA;
    unsigned short* hd=(i&1)?hnA:hnB;
    k_layer<<<B_*(N_/64),256,0,stream>>>(hs,hd,offT,srcs2,wcat+(size_t)i*8192,
        brel+(size_t)i*64,lng,lnb,(i<3)?1:0);
  }
  // after 4 layers (A->B->A->B->A) result is in hnA
  {
    int MT=B_*(G_+F_);
    k_readout2<<<(MT+255)/256,256,0,stream>>>(hnA,prodi,linei,pw,pb,fw,fb,outp,outf,pfhi,pflo);
  }
  k_md_gemm<<<512,256,0,stream>>>(gm,lm,pfhi,pflo,outmd);
}